// Round 11
// baseline (244.457 us; speedup 1.0000x reference)
//
#include <hip/hip_runtime.h>
#include <hip/hip_fp16.h>
#include <math.h>

#define N_NODES 50000
#define E_EDGES 1600000
#define G_GRAPHS 512
#define IN_DIM 64
#define EMBED 128
#define HD 128
#define NHEAD 4
#define D1 128
#define D2 64
#define D3 16
#define NEG_SLOPE 0.2f
#define NB ((N_NODES + 127) >> 7)                       // 391 coarse buckets (128 nodes)
#define HT_TILE 4096
#define HT_BLOCKS ((E_EDGES + HT_TILE - 1) / HT_TILE)   // 391 (k0hg hist tiles)
#define PT_TILE 8192
#define PT_BLOCKS ((E_EDGES + PT_TILE - 1) / PT_TILE)   // 196 (partition tiles)
#define K1_TILES ((N_NODES + 63) / 64)                  // 782 (GEMM tiles)
#define FB_CAP 8192
#define M2_EDGE_BLK ((E_EDGES + 2047) / 2048)           // 782 edge blocks @512thr x4
#define K6_HALF 6250                                    // quads per k6 half-dispatch

typedef float vfloat4 __attribute__((ext_vector_type(4)));
typedef float vfloat2 __attribute__((ext_vector_type(2)));
typedef unsigned short ushort_t;

static __device__ __forceinline__ float leaky(float x) { return x > 0.f ? x : NEG_SLOPE * x; }

// K0+HG: blocks [0,HT_BLOCKS) coarse dst-histogram (4-way per-wave LDS hist to cut
// atomic contention — pt's proven pattern); rest Wc/bc.
__global__ void __launch_bounds__(256) k0hg(const int* __restrict__ dst, int* __restrict__ ghist,
                                            const float* __restrict__ W0, const float* __restrict__ b0,
                                            const float* __restrict__ Wfc, float* __restrict__ Wc,
                                            float* __restrict__ bc) {
    __shared__ int lh[4][NB];
    const int t = threadIdx.x;
    if (blockIdx.x < HT_BLOCKS) {
        const int wid = t >> 6;
        for (int i = t; i < NB; i += 256) {
            lh[0][i] = 0; lh[1][i] = 0; lh[2][i] = 0; lh[3][i] = 0;
        }
        __syncthreads();
        const long e0 = (long)blockIdx.x * HT_TILE;
#pragma unroll
        for (int k = 0; k < HT_TILE / 256; ++k) {
            long e = e0 + t + k * 256;
            if (e < E_EDGES) atomicAdd(&lh[wid][dst[e] >> 7], 1);
        }
        __syncthreads();
        for (int i = t; i < NB; i += 256) {
            int v = lh[0][i] + lh[1][i] + lh[2][i] + lh[3][i];
            if (v) atomicAdd(&ghist[i], v);
        }
    } else {
        int tid = (int)(blockIdx.x - HT_BLOCKS) * 256 + t;
        if (tid < IN_DIM * HD) {
            int i = tid >> 7, j = tid & 127;
            float acc = 0.f;
            for (int k = 0; k < EMBED; ++k) acc += W0[i * EMBED + k] * Wfc[k * HD + j];
            Wc[tid] = acc;
        } else if (tid < IN_DIM * HD + HD) {
            int j = tid - IN_DIM * HD;
            float acc = 0.f;
            for (int k = 0; k < EMBED; ++k) acc += b0[k] * Wfc[k * HD + j];
            bc[j] = acc;
        }
    }
}

// K1PT (R10 body): blocks [0,K1_TILES) = k1 GEMM; rest = pt partition @TILE 8192.
#define SMEM_BYTES 53248
__global__ void __launch_bounds__(256) k1pt(
    const float* __restrict__ A, const float* __restrict__ W,
    const float* __restrict__ b, const float* __restrict__ attn_l,
    const float* __restrict__ attn_r,
    const int* __restrict__ src, const int* __restrict__ dst,
    const int* __restrict__ ghist, int* __restrict__ cursor0,
    unsigned char* __restrict__ feat, float* __restrict__ el,
    float* __restrict__ er, unsigned int* __restrict__ part) {
    __shared__ __align__(16) char smem[SMEM_BYTES];
    const int t = threadIdx.x;
    if (blockIdx.x < K1_TILES) {
        float* Ws = (float*)smem;                         // 32 KB [k][c]
        float(*As)[68] = (float(*)[68])(smem + 32768);    // 17 KB [row][k]
        const int cc = t & 31, rt = t >> 5;
        const int c0 = cc * 4, r0 = rt * 8;
        const int row0 = (int)blockIdx.x * 64;
        {
            const float4* Wg = (const float4*)W;
            float4* Wl = (float4*)Ws;
#pragma unroll
            for (int j = 0; j < (IN_DIM * HD / 4) / 256; ++j) Wl[t + j * 256] = Wg[t + j * 256];
        }
#pragma unroll
        for (int j = 0; j < 4; ++j) {
            int i2 = t + j * 256;
            int row = i2 >> 4, kq = i2 & 15;
            int gr = row0 + row;
            float4 v = (gr < N_NODES) ? *(const float4*)(A + (size_t)gr * IN_DIM + kq * 4)
                                      : make_float4(0.f, 0.f, 0.f, 0.f);
            *(float4*)&As[row][kq * 4] = v;
        }
        __syncthreads();
        float acc[8][4];
#pragma unroll
        for (int i = 0; i < 8; ++i)
#pragma unroll
            for (int j = 0; j < 4; ++j) acc[i][j] = 0.f;
        for (int k4 = 0; k4 < IN_DIM / 4; ++k4) {
            vfloat4 w0 = *(const vfloat4*)&Ws[(k4 * 4 + 0) * HD + c0];
            vfloat4 w1 = *(const vfloat4*)&Ws[(k4 * 4 + 1) * HD + c0];
            vfloat4 w2 = *(const vfloat4*)&Ws[(k4 * 4 + 2) * HD + c0];
            vfloat4 w3 = *(const vfloat4*)&Ws[(k4 * 4 + 3) * HD + c0];
#pragma unroll
            for (int i = 0; i < 8; ++i) {
                vfloat4 a = *(const vfloat4*)&As[r0 + i][k4 * 4];
#pragma unroll
                for (int j = 0; j < 4; ++j)
                    acc[i][j] += a.x * w0[j] + a.y * w1[j] + a.z * w2[j] + a.w * w3[j];
            }
        }
        {
            vfloat4 bcv = *(const vfloat4*)(b + c0);
#pragma unroll
            for (int i = 0; i < 8; ++i)
#pragma unroll
                for (int j = 0; j < 4; ++j) acc[i][j] += bcv[j];
        }
#pragma unroll
        for (int i = 0; i < 8; ++i) {
            int gr = row0 + r0 + i;
            if (gr < N_NODES) {
                unsigned int ww = __builtin_amdgcn_cvt_pk_fp8_f32(acc[i][0], acc[i][1], 0, false);
                ww = __builtin_amdgcn_cvt_pk_fp8_f32(acc[i][2], acc[i][3], ww, true);
                *(unsigned int*)(feat + (size_t)gr * HD + c0) = ww;
            }
        }
        {
            vfloat4 al = *(const vfloat4*)(attn_l + c0);
            vfloat4 ar = *(const vfloat4*)(attn_r + c0);
            float pl[8], pr[8];
#pragma unroll
            for (int i = 0; i < 8; ++i) {
                pl[i] = acc[i][0] * al[0] + acc[i][1] * al[1] + acc[i][2] * al[2] + acc[i][3] * al[3];
                pr[i] = acc[i][0] * ar[0] + acc[i][1] * ar[1] + acc[i][2] * ar[2] + acc[i][3] * ar[3];
            }
#pragma unroll
            for (int off = 1; off <= 4; off <<= 1) {
#pragma unroll
                for (int i = 0; i < 8; ++i) {
                    pl[i] += __shfl_xor(pl[i], off);
                    pr[i] += __shfl_xor(pr[i], off);
                }
            }
            if ((cc & 7) == 0) {
                const int h = cc >> 3;
#pragma unroll
                for (int i = 0; i < 8; ++i) {
                    int gr = row0 + r0 + i;
                    if (gr < N_NODES) {
                        el[gr * 4 + h] = pl[i];
                        er[gr * 4 + h] = pr[i];
                    }
                }
            }
        }
    } else {
        int(*hist)[NB] = (int(*)[NB])smem;                   // 6256 B
        int(*lcur)[NB] = (int(*)[NB])(smem + 6256);          // 6256 B
        int* tot = (int*)(smem + 12512);
        int* offs = (int*)(smem + 14076);
        int* base_s = (int*)(smem + 15640);
        int* gt = (int*)(smem + 17204);
        int* offsG = (int*)(smem + 18768);
        unsigned int* stage = (unsigned int*)(smem + 20336); // 32 KB
        const int lane = t & 63, wid = t >> 6;
        const int tile = (int)blockIdx.x - K1_TILES;
        const long e0 = (long)tile * PT_TILE;
        const int cnt = (int)min((long)PT_TILE, (long)E_EDGES - e0);
        for (int i = t; i < NB; i += 256) {
            hist[0][i] = 0; hist[1][i] = 0; hist[2][i] = 0; hist[3][i] = 0;
            gt[i] = ghist[i];
        }
        __syncthreads();
        unsigned int v[PT_TILE / 256];
#pragma unroll
        for (int k = 0; k < PT_TILE / 256; ++k) {
            int i = t + k * 256;
            if (i < cnt) {
                int d = dst[e0 + i];
                v[k] = ((unsigned int)d << 16) | (unsigned int)src[e0 + i];
                atomicAdd(&hist[wid][d >> 7], 1);
            } else v[k] = 0xFFFFFFFFu;
        }
        __syncthreads();
        for (int i = t; i < NB; i += 256) {
            int h0 = hist[0][i], h1 = hist[1][i], h2 = hist[2][i], h3 = hist[3][i];
            hist[0][i] = 0; hist[1][i] = h0; hist[2][i] = h0 + h1; hist[3][i] = h0 + h1 + h2;
            tot[i] = h0 + h1 + h2 + h3;
        }
        __syncthreads();
        if (wid == 0) {
            int run = 0;
            for (int c = 0; c < (NB + 63) / 64; ++c) {
                int i = c * 64 + lane;
                int vv = (i < NB) ? tot[i] : 0;
                int incl = vv;
#pragma unroll
                for (int off = 1; off < 64; off <<= 1) {
                    int o = __shfl_up(incl, off, 64);
                    if (lane >= off) incl += o;
                }
                if (i < NB) offs[i] = run + incl - vv;
                run += __shfl(incl, 63, 64);
            }
        } else if (wid == 1) {
            int run = 0;
            for (int c = 0; c < (NB + 63) / 64; ++c) {
                int i = c * 64 + lane;
                int vv = (i < NB) ? gt[i] : 0;
                int incl = vv;
#pragma unroll
                for (int off = 1; off < 64; off <<= 1) {
                    int o = __shfl_up(incl, off, 64);
                    if (lane >= off) incl += o;
                }
                if (i < NB) offsG[i] = run + incl - vv;
                run += __shfl(incl, 63, 64);
            }
        }
        __syncthreads();
        for (int i = t; i < NB; i += 256) {
            int tt2 = tot[i];
            base_s[i] = offsG[i] + (tt2 ? atomicAdd(&cursor0[i], tt2) : 0);
            int ob = offs[i];
            lcur[0][i] = ob + hist[0][i];
            lcur[1][i] = ob + hist[1][i];
            lcur[2][i] = ob + hist[2][i];
            lcur[3][i] = ob + hist[3][i];
        }
        __syncthreads();
#pragma unroll
        for (int k = 0; k < PT_TILE / 256; ++k) {
            if (v[k] != 0xFFFFFFFFu) {
                int bb = v[k] >> 23;
                int pos = atomicAdd(&lcur[wid][bb], 1);
                stage[pos] = v[k];
            }
        }
        __syncthreads();
        for (int i = t; i < cnt; i += 256) {
            unsigned int p = stage[i];
            int bb = p >> 23;
            part[base_s[bb] + (i - offs[bb])] = p & 0x7FFFFFu;  // (dst&127)<<16 | src
        }
    }
}

// FB: fine fill. SINGLE part read: bucket entries stashed in LDS (32 KB) during the
// histogram pass; scatter reads LDS. Saves a 6.4 MB global re-read.
__global__ void __launch_bounds__(256) fb_fill(const unsigned int* __restrict__ part,
                                               const int* __restrict__ ghist,
                                               int* __restrict__ rowstart,
                                               ushort_t* __restrict__ csr_src) {
    const int b = blockIdx.x, t = threadIdx.x, lane = t & 63, wid = t >> 6;
    __shared__ int degl[4][128], totl[128], offl[128], curl[4][128];
    __shared__ int red[4], s0s[2];
    __shared__ unsigned int lpart[FB_CAP];  // 32 KB
    __shared__ ushort_t lsrc[FB_CAP];       // 16 KB
    {
        int partial = 0;
        for (int i = t; i < b; i += 256) partial += ghist[i];
#pragma unroll
        for (int off = 32; off; off >>= 1) partial += __shfl_xor(partial, off);
        if (lane == 0) red[wid] = partial;
        if (t < 128) { degl[0][t] = 0; degl[1][t] = 0; degl[2][t] = 0; degl[3][t] = 0; }
        __syncthreads();
        if (t == 0) {
            int s0 = red[0] + red[1] + red[2] + red[3];
            s0s[0] = s0;
            s0s[1] = s0 + ghist[b];
        }
        __syncthreads();
    }
    const int s0 = s0s[0], s1 = s0s[1];
    const int cnt = s1 - s0;
    if (cnt <= FB_CAP) {
        for (int i = t; i < cnt; i += 256) {
            unsigned int p = part[s0 + i];
            lpart[i] = p;
            atomicAdd(&degl[wid][p >> 16], 1);
        }
    } else {
        for (int i = t; i < cnt; i += 256) {
            unsigned int p = part[s0 + i];
            atomicAdd(&degl[wid][p >> 16], 1);
        }
    }
    __syncthreads();
    if (t < 128) {
        int d0 = degl[0][t], d1 = degl[1][t], d2 = degl[2][t], d3 = degl[3][t];
        degl[0][t] = 0; degl[1][t] = d0; degl[2][t] = d0 + d1; degl[3][t] = d0 + d1 + d2;
        totl[t] = d0 + d1 + d2 + d3;
    }
    __syncthreads();
    if (wid == 0) {
        int run = 0;
        for (int c = 0; c < 2; ++c) {
            int i = c * 64 + lane;
            int vv = totl[i];
            int incl = vv;
#pragma unroll
            for (int off = 1; off < 64; off <<= 1) {
                int o = __shfl_up(incl, off, 64);
                if (lane >= off) incl += o;
            }
            offl[i] = run + incl - vv;
            run += __shfl(incl, 63, 64);
        }
    }
    __syncthreads();
    if (t < 128) {
        int ob = offl[t];
        curl[0][t] = ob + degl[0][t];
        curl[1][t] = ob + degl[1][t];
        curl[2][t] = ob + degl[2][t];
        curl[3][t] = ob + degl[3][t];
        int node = (b << 7) + t;
        if (node < N_NODES) rowstart[node] = s0 + ob;
    }
    if (b == 0 && t == 0) rowstart[N_NODES] = E_EDGES;
    __syncthreads();
    if (cnt <= FB_CAP) {
        for (int i = t; i < cnt; i += 256) {
            unsigned int p = lpart[i];
            int pos = atomicAdd(&curl[wid][p >> 16], 1);
            lsrc[pos] = (ushort_t)(p & 0xFFFFu);
        }
        __syncthreads();
        for (int i = t; i < cnt; i += 256) csr_src[s0 + i] = lsrc[i];
    } else {
        for (int i = t; i < cnt; i += 256) {
            unsigned int p = part[s0 + i];
            int pos = atomicAdd(&curl[wid][p >> 16], 1);
            csr_src[s0 + pos] = (ushort_t)(p & 0xFFFFu);
        }
    }
}

// K6 (R9 body, proven ~46 us): per-dst softmax + aggregation. Launched as TWO
// half-dispatches (node_base = 0 / 25000) so top-5 profiling can expose the next
// largest kernel; body byte-identical.
__global__ void __launch_bounds__(256) k6_aggregate(
    const ushort_t* __restrict__ csr_src, const int* __restrict__ rowstart,
    const float* __restrict__ el, const float* __restrict__ er,
    const unsigned char* __restrict__ feat, const float* __restrict__ gat_bias,
    float* __restrict__ er_rd, float* __restrict__ hn, int node_base) {
    __shared__ uint2 s_pk[4][64][4];  // [wave][edge][head] = {src<<7, ex bits}, 8 KB
    const int wid = threadIdx.x >> 6;
    const int lane = threadIdx.x & 63;
    const int n = node_base + blockIdx.x * 4 + wid;
    if (n >= N_NODES) return;
    const int start = rowstart[n];
    const int end = rowstart[n + 1];
    const int deg = end - start;

    const int e0 = lane >> 2;
    const int h = lane & 3;
    const float erh = er[n * 4 + h];
    float sm = 0.f;
    for (int base = 0; base < deg; base += 16) {
        const int e = base + e0;
        if (e < deg) {
            const int s = csr_src[start + e];
            const float ex = __expf(leaky(el[s * 4 + h] + erh));
            sm += ex;
            if (e < 64)
                s_pk[wid][e][h] = make_uint2((unsigned int)s << 7, __float_as_uint(ex));
        }
    }
#pragma unroll
    for (int off = 4; off <= 32; off <<= 1) sm += __shfl_xor(sm, off);
    const float rd = sm > 0.f ? 1.f / sm : 0.f;
    if (lane < 4) {
        er_rd[(size_t)n * 8 + lane] = erh;
        er_rd[(size_t)n * 8 + 4 + lane] = rd;
    }

    const int g4 = lane >> 4, gl = lane & 15;
    const int h2 = gl >> 2;
    const float rdh = __shfl(rd, h2);
    vfloat2 acc0 = {0.f, 0.f}, acc1 = {0.f, 0.f}, acc2 = {0.f, 0.f}, acc3 = {0.f, 0.f};

    if (deg <= 64) {
        const uint2* pk = &s_pk[wid][0][h2];
        const unsigned char* fg = feat + (gl << 3);
        int idx = g4;
        for (; idx + 4 < deg; idx += 8) {
            const uint2 pA = pk[idx * 4];
            const uint2 pB = pk[(idx + 4) * 4];
            const uint2 wA = *(const uint2*)(fg + pA.x);
            const uint2 wB = *(const uint2*)(fg + pB.x);
            const float exA = __uint_as_float(pA.y);
            const float exB = __uint_as_float(pB.y);
            const vfloat2 eA = {exA, exA}, eB = {exB, exB};
            acc0 += eA * __builtin_amdgcn_cvt_pk_f32_fp8(wA.x, false);
            acc1 += eA * __builtin_amdgcn_cvt_pk_f32_fp8(wA.x, true);
            acc2 += eA * __builtin_amdgcn_cvt_pk_f32_fp8(wA.y, false);
            acc3 += eA * __builtin_amdgcn_cvt_pk_f32_fp8(wA.y, true);
            acc0 += eB * __builtin_amdgcn_cvt_pk_f32_fp8(wB.x, false);
            acc1 += eB * __builtin_amdgcn_cvt_pk_f32_fp8(wB.x, true);
            acc2 += eB * __builtin_amdgcn_cvt_pk_f32_fp8(wB.y, false);
            acc3 += eB * __builtin_amdgcn_cvt_pk_f32_fp8(wB.y, true);
        }
        if (idx < deg) {
            const uint2 p = pk[idx * 4];
            const uint2 w = *(const uint2*)(fg + p.x);
            const float ex = __uint_as_float(p.y);
            const vfloat2 ev = {ex, ex};
            acc0 += ev * __builtin_amdgcn_cvt_pk_f32_fp8(w.x, false);
            acc1 += ev * __builtin_amdgcn_cvt_pk_f32_fp8(w.x, true);
            acc2 += ev * __builtin_amdgcn_cvt_pk_f32_fp8(w.y, false);
            acc3 += ev * __builtin_amdgcn_cvt_pk_f32_fp8(w.y, true);
        }
    } else {
        const float erh2 = __shfl(erh, h2);
        const unsigned char* fg = feat + (gl << 3);
        for (int e = start + g4; e < end; e += 4) {
            const unsigned int s = csr_src[e];
            const float ex = __expf(leaky(el[s * 4 + h2] + erh2));
            const vfloat2 ev = {ex, ex};
            const uint2 w = *(const uint2*)(fg + ((size_t)s << 7));
            acc0 += ev * __builtin_amdgcn_cvt_pk_f32_fp8(w.x, false);
            acc1 += ev * __builtin_amdgcn_cvt_pk_f32_fp8(w.x, true);
            acc2 += ev * __builtin_amdgcn_cvt_pk_f32_fp8(w.y, false);
            acc3 += ev * __builtin_amdgcn_cvt_pk_f32_fp8(w.y, true);
        }
    }
    {
        const vfloat2 rv = {rdh, rdh};
        acc0 *= rv; acc1 *= rv; acc2 *= rv; acc3 *= rv;
    }
#pragma unroll
    for (int off = 16; off <= 32; off <<= 1) {
        acc0.x += __shfl_xor(acc0.x, off);
        acc0.y += __shfl_xor(acc0.y, off);
        acc1.x += __shfl_xor(acc1.x, off);
        acc1.y += __shfl_xor(acc1.y, off);
        acc2.x += __shfl_xor(acc2.x, off);
        acc2.y += __shfl_xor(acc2.y, off);
        acc3.x += __shfl_xor(acc3.x, off);
        acc3.y += __shfl_xor(acc3.y, off);
    }
    if (lane < 16) {
        const float4 b0 = ((const float4*)gat_bias)[gl * 2];
        const float4 b1 = ((const float4*)gat_bias)[gl * 2 + 1];
        float4* hp = (float4*)(hn + (size_t)n * HD + gl * 8);
        hp[0] = make_float4(acc0.x + b0.x, acc0.y + b0.y, acc1.x + b0.z, acc1.y + b0.w);
        hp[1] = make_float4(acc2.x + b1.x, acc2.y + b1.y, acc3.x + b1.z, acc3.y + b1.w);
    }
}

// M2B: blocks [0,G_GRAPHS) = k7 pool+MLP (R9 body). Blocks [G_GRAPHS,+M2_EDGE_BLK)
// = attention in edge order, 4 CONSECUTIVE edges/thread: int4 src/dst loads
// (16 B/lane) + 4 consecutive float4 stores (64 B contiguous per lane).
__global__ void __launch_bounds__(512) m2b_mlp_attn(
    const int* __restrict__ src, const int* __restrict__ dst,
    const float* __restrict__ el, const float* __restrict__ er_rd,
    const float* __restrict__ hn, const int* __restrict__ graph_ids,
    const float* __restrict__ W1, const float* __restrict__ b1,
    const float* __restrict__ W2, const float* __restrict__ b2,
    const float* __restrict__ W3, const float* __restrict__ b3,
    float* __restrict__ a_out, float* __restrict__ out) {
    const int t = threadIdx.x;
    if (blockIdx.x < G_GRAPHS) {
        const int g = (int)blockIdx.x;
        const int tt = t & 127, part = t >> 7;
        __shared__ int bounds[2];
        __shared__ double pool[4][128];
        __shared__ double x[128], y[128];
        if (t < 2) {
            const int target = g + t;
            int lo = 0, hi = N_NODES;
            while (lo < hi) {
                int mid = (lo + hi) >> 1;
                if (graph_ids[mid] < target) lo = mid + 1; else hi = mid;
            }
            bounds[t] = lo;
        }
        __syncthreads();
        const int lo = bounds[0], hi = bounds[1];
        double s = 0.0;
        for (int n = lo + part; n < hi; n += 4) s += (double)hn[(size_t)n * HD + tt];
        pool[part][tt] = s;
        __syncthreads();
        if (t < 128) {
            const double cnt = (double)(hi - lo);
            const double sum = pool[0][t] + pool[1][t] + pool[2][t] + pool[3][t];
            const double v = sum / fmax(cnt, 1.0);
            x[t] = v > 0.0 ? v : expm1(v);
        }
        __syncthreads();
        if (t < 128) {
            double acc = (double)b1[t];
            for (int k = 0; k < HD; ++k) acc += x[k] * (double)W1[k * D1 + t];
            y[t] = acc > 0.0 ? acc : expm1(acc);
        }
        __syncthreads();
        if (t < D2) {
            double a2 = (double)b2[t];
            for (int k = 0; k < D1; ++k) a2 += y[k] * (double)W2[k * D2 + t];
            x[t] = a2 > 0.0 ? a2 : expm1(a2);
        }
        __syncthreads();
        if (t < D3) {
            double a3 = (double)b3[t];
            for (int k = 0; k < D2; ++k) a3 += x[k] * (double)W3[k * D3 + t];
            out[g * D3 + t] = (float)a3;
        }
    } else {
        const long base4 = (long)(blockIdx.x - G_GRAPHS) * 2048 + (long)t * 4;
        if (base4 + 3 < E_EDGES) {
            const int4 s4 = *(const int4*)(src + base4);
            const int4 d4 = *(const int4*)(dst + base4);
            const int sx[4] = {s4.x, s4.y, s4.z, s4.w};
            const int dx[4] = {d4.x, d4.y, d4.z, d4.w};
            float4 el4[4], er4[4], r4[4];
#pragma unroll
            for (int k = 0; k < 4; ++k) {
                el4[k] = *(const float4*)(el + sx[k] * 4);
                er4[k] = *(const float4*)(er_rd + (size_t)dx[k] * 8);
                r4[k] = *(const float4*)(er_rd + (size_t)dx[k] * 8 + 4);
            }
#pragma unroll
            for (int k = 0; k < 4; ++k) {
                vfloat4 a;
                a.x = __expf(leaky(el4[k].x + er4[k].x)) * r4[k].x;
                a.y = __expf(leaky(el4[k].y + er4[k].y)) * r4[k].y;
                a.z = __expf(leaky(el4[k].z + er4[k].z)) * r4[k].z;
                a.w = __expf(leaky(el4[k].w + er4[k].w)) * r4[k].w;
                __builtin_nontemporal_store(a, (vfloat4*)a_out + (base4 + k));
            }
        } else {
            for (int k = 0; k < 4; ++k) {
                const long e = base4 + k;
                if (e < E_EDGES) {
                    const int s = src[e], d = dst[e];
                    const float4 el4 = *(const float4*)(el + s * 4);
                    const float4 er4 = *(const float4*)(er_rd + (size_t)d * 8);
                    const float4 r4 = *(const float4*)(er_rd + (size_t)d * 8 + 4);
                    vfloat4 a;
                    a.x = __expf(leaky(el4.x + er4.x)) * r4.x;
                    a.y = __expf(leaky(el4.y + er4.y)) * r4.y;
                    a.z = __expf(leaky(el4.z + er4.z)) * r4.z;
                    a.w = __expf(leaky(el4.w + er4.w)) * r4.w;
                    __builtin_nontemporal_store(a, (vfloat4*)a_out + e);
                }
            }
        }
    }
}

extern "C" void kernel_launch(void* const* d_in, const int* in_sizes, int n_in,
                              void* d_out, int out_size, void* d_ws, size_t ws_size,
                              hipStream_t stream) {
    const float* feature = (const float*)d_in[0];
    const int* src = (const int*)d_in[1];
    const int* dst = (const int*)d_in[2];
    const int* graph_ids = (const int*)d_in[3];
    const float* W0 = (const float*)d_in[4];
    const float* b0 = (const float*)d_in[5];
    const float* Wfc = (const float*)d_in[6];
    const float* attn_l = (const float*)d_in[7];
    const float* attn_r = (const float*)d_in[8];
    const float* gat_bias = (const float*)d_in[9];
    const float* W1 = (const float*)d_in[10];
    const float* b1 = (const float*)d_in[11];
    const float* W2 = (const float*)d_in[12];
    const float* b2 = (const float*)d_in[13];
    const float* W3 = (const float*)d_in[14];
    const float* b3 = (const float*)d_in[15];

    char* ws = (char*)d_ws;
    size_t off = 0;
    auto carve = [&](size_t bytes) -> void* {
        void* p = ws + off;
        off += (bytes + 255) & ~(size_t)255;
        return p;
    };
    int* ghist = (int*)carve((size_t)NB * 4);
    int* cursor0 = (int*)carve((size_t)NB * 4);
    const size_t zero_span = off;                       // ghist + cursor0
    float* Wc = (float*)carve((size_t)IN_DIM * HD * 4);
    float* bc = (float*)carve((size_t)HD * 4);
    unsigned char* feat = (unsigned char*)carve((size_t)N_NODES * HD);
    float* el = (float*)carve((size_t)N_NODES * 4 * 4);
    float* er = (float*)carve((size_t)N_NODES * 4 * 4);
    float* er_rd = (float*)carve((size_t)N_NODES * 8 * 4);
    int* rowstart = (int*)carve((size_t)(N_NODES + 1) * 4);
    unsigned int* part = (unsigned int*)carve((size_t)E_EDGES * 4);
    ushort_t* csr_src = (ushort_t*)carve((size_t)E_EDGES * 2);
    float* hn = (float*)carve((size_t)N_NODES * HD * 4);

    float* out = (float*)d_out;
    float* a_out = out + G_GRAPHS * D3;

    (void)hipMemsetAsync(d_ws, 0, zero_span, stream);
    k0hg<<<HT_BLOCKS + 33, 256, 0, stream>>>(dst, ghist, W0, b0, Wfc, Wc, bc);
    k1pt<<<K1_TILES + PT_BLOCKS, 256, 0, stream>>>(feature, Wc, bc, attn_l, attn_r,
                                                   src, dst, ghist, cursor0,
                                                   feat, el, er, part);
    fb_fill<<<NB, 256, 0, stream>>>(part, ghist, rowstart, csr_src);
    k6_aggregate<<<K6_HALF, 256, 0, stream>>>(csr_src, rowstart, el, er, feat,
                                              gat_bias, er_rd, hn, 0);
    k6_aggregate<<<K6_HALF, 256, 0, stream>>>(csr_src, rowstart, el, er, feat,
                                              gat_bias, er_rd, hn, 25000);
    m2b_mlp_attn<<<G_GRAPHS + M2_EDGE_BLK, 512, 0, stream>>>(src, dst, el, er_rd, hn,
                                                             graph_ids, W1, b1, W2, b2,
                                                             W3, b3, a_out, out);
}

// Round 12
// 233.329 us; speedup vs baseline: 1.0477x; 1.0477x over previous
//
#include <hip/hip_runtime.h>
#include <hip/hip_fp16.h>
#include <math.h>

#define N_NODES 50000
#define E_EDGES 1600000
#define G_GRAPHS 512
#define IN_DIM 64
#define EMBED 128
#define HD 128
#define NHEAD 4
#define D1 128
#define D2 64
#define D3 16
#define NEG_SLOPE 0.2f
#define NB ((N_NODES + 127) >> 7)                       // 391 coarse buckets (128 nodes)
#define HT_TILE 4096
#define HT_BLOCKS ((E_EDGES + HT_TILE - 1) / HT_TILE)   // 391 (k0hg hist tiles)
#define PT_TILE 8192
#define PT_BLOCKS ((E_EDGES + PT_TILE - 1) / PT_TILE)   // 196 (partition tiles)
#define K1_TILES ((N_NODES + 63) / 64)                  // 782 (GEMM tiles)
#define FB_CAP 8192
#define M2_EDGE_BLK ((E_EDGES + 4095) / 4096)           // 391 edge blocks @512thr x8
#define M2_FULL (E_EDGES / 4096)                        // 390 full blocks

typedef float vfloat4 __attribute__((ext_vector_type(4)));
typedef float vfloat2 __attribute__((ext_vector_type(2)));
typedef unsigned short ushort_t;

static __device__ __forceinline__ float leaky(float x) { return x > 0.f ? x : NEG_SLOPE * x; }

// K0+HG: blocks [0,HT_BLOCKS) coarse dst-histogram (4-way per-wave LDS hist);
// rest Wc = W0@Wfc, bc = b0@Wfc.
__global__ void __launch_bounds__(256) k0hg(const int* __restrict__ dst, int* __restrict__ ghist,
                                            const float* __restrict__ W0, const float* __restrict__ b0,
                                            const float* __restrict__ Wfc, float* __restrict__ Wc,
                                            float* __restrict__ bc) {
    __shared__ int lh[4][NB];
    const int t = threadIdx.x;
    if (blockIdx.x < HT_BLOCKS) {
        const int wid = t >> 6;
        for (int i = t; i < NB; i += 256) {
            lh[0][i] = 0; lh[1][i] = 0; lh[2][i] = 0; lh[3][i] = 0;
        }
        __syncthreads();
        const long e0 = (long)blockIdx.x * HT_TILE;
#pragma unroll
        for (int k = 0; k < HT_TILE / 256; ++k) {
            long e = e0 + t + k * 256;
            if (e < E_EDGES) atomicAdd(&lh[wid][dst[e] >> 7], 1);
        }
        __syncthreads();
        for (int i = t; i < NB; i += 256) {
            int v = lh[0][i] + lh[1][i] + lh[2][i] + lh[3][i];
            if (v) atomicAdd(&ghist[i], v);
        }
    } else {
        int tid = (int)(blockIdx.x - HT_BLOCKS) * 256 + t;
        if (tid < IN_DIM * HD) {
            int i = tid >> 7, j = tid & 127;
            float acc = 0.f;
            for (int k = 0; k < EMBED; ++k) acc += W0[i * EMBED + k] * Wfc[k * HD + j];
            Wc[tid] = acc;
        } else if (tid < IN_DIM * HD + HD) {
            int j = tid - IN_DIM * HD;
            float acc = 0.f;
            for (int k = 0; k < EMBED; ++k) acc += b0[k] * Wfc[k * HD + j];
            bc[j] = acc;
        }
    }
}

// K1PT (R10 body): blocks [0,K1_TILES) = k1 GEMM; rest = pt partition @TILE 8192.
#define SMEM_BYTES 53248
__global__ void __launch_bounds__(256) k1pt(
    const float* __restrict__ A, const float* __restrict__ W,
    const float* __restrict__ b, const float* __restrict__ attn_l,
    const float* __restrict__ attn_r,
    const int* __restrict__ src, const int* __restrict__ dst,
    const int* __restrict__ ghist, int* __restrict__ cursor0,
    unsigned char* __restrict__ feat, float* __restrict__ el,
    float* __restrict__ er, unsigned int* __restrict__ part) {
    __shared__ __align__(16) char smem[SMEM_BYTES];
    const int t = threadIdx.x;
    if (blockIdx.x < K1_TILES) {
        float* Ws = (float*)smem;                         // 32 KB [k][c]
        float(*As)[68] = (float(*)[68])(smem + 32768);    // 17 KB [row][k]
        const int cc = t & 31, rt = t >> 5;
        const int c0 = cc * 4, r0 = rt * 8;
        const int row0 = (int)blockIdx.x * 64;
        {
            const float4* Wg = (const float4*)W;
            float4* Wl = (float4*)Ws;
#pragma unroll
            for (int j = 0; j < (IN_DIM * HD / 4) / 256; ++j) Wl[t + j * 256] = Wg[t + j * 256];
        }
#pragma unroll
        for (int j = 0; j < 4; ++j) {
            int i2 = t + j * 256;
            int row = i2 >> 4, kq = i2 & 15;
            int gr = row0 + row;
            float4 v = (gr < N_NODES) ? *(const float4*)(A + (size_t)gr * IN_DIM + kq * 4)
                                      : make_float4(0.f, 0.f, 0.f, 0.f);
            *(float4*)&As[row][kq * 4] = v;
        }
        __syncthreads();
        float acc[8][4];
#pragma unroll
        for (int i = 0; i < 8; ++i)
#pragma unroll
            for (int j = 0; j < 4; ++j) acc[i][j] = 0.f;
        for (int k4 = 0; k4 < IN_DIM / 4; ++k4) {
            vfloat4 w0 = *(const vfloat4*)&Ws[(k4 * 4 + 0) * HD + c0];
            vfloat4 w1 = *(const vfloat4*)&Ws[(k4 * 4 + 1) * HD + c0];
            vfloat4 w2 = *(const vfloat4*)&Ws[(k4 * 4 + 2) * HD + c0];
            vfloat4 w3 = *(const vfloat4*)&Ws[(k4 * 4 + 3) * HD + c0];
#pragma unroll
            for (int i = 0; i < 8; ++i) {
                vfloat4 a = *(const vfloat4*)&As[r0 + i][k4 * 4];
#pragma unroll
                for (int j = 0; j < 4; ++j)
                    acc[i][j] += a.x * w0[j] + a.y * w1[j] + a.z * w2[j] + a.w * w3[j];
            }
        }
        {
            vfloat4 bcv = *(const vfloat4*)(b + c0);
#pragma unroll
            for (int i = 0; i < 8; ++i)
#pragma unroll
                for (int j = 0; j < 4; ++j) acc[i][j] += bcv[j];
        }
#pragma unroll
        for (int i = 0; i < 8; ++i) {
            int gr = row0 + r0 + i;
            if (gr < N_NODES) {
                unsigned int ww = __builtin_amdgcn_cvt_pk_fp8_f32(acc[i][0], acc[i][1], 0, false);
                ww = __builtin_amdgcn_cvt_pk_fp8_f32(acc[i][2], acc[i][3], ww, true);
                *(unsigned int*)(feat + (size_t)gr * HD + c0) = ww;
            }
        }
        {
            vfloat4 al = *(const vfloat4*)(attn_l + c0);
            vfloat4 ar = *(const vfloat4*)(attn_r + c0);
            float pl[8], pr[8];
#pragma unroll
            for (int i = 0; i < 8; ++i) {
                pl[i] = acc[i][0] * al[0] + acc[i][1] * al[1] + acc[i][2] * al[2] + acc[i][3] * al[3];
                pr[i] = acc[i][0] * ar[0] + acc[i][1] * ar[1] + acc[i][2] * ar[2] + acc[i][3] * ar[3];
            }
#pragma unroll
            for (int off = 1; off <= 4; off <<= 1) {
#pragma unroll
                for (int i = 0; i < 8; ++i) {
                    pl[i] += __shfl_xor(pl[i], off);
                    pr[i] += __shfl_xor(pr[i], off);
                }
            }
            if ((cc & 7) == 0) {
                const int h = cc >> 3;
#pragma unroll
                for (int i = 0; i < 8; ++i) {
                    int gr = row0 + r0 + i;
                    if (gr < N_NODES) {
                        el[gr * 4 + h] = pl[i];
                        er[gr * 4 + h] = pr[i];
                    }
                }
            }
        }
    } else {
        int(*hist)[NB] = (int(*)[NB])smem;                   // 6256 B
        int(*lcur)[NB] = (int(*)[NB])(smem + 6256);          // 6256 B
        int* tot = (int*)(smem + 12512);
        int* offs = (int*)(smem + 14076);
        int* base_s = (int*)(smem + 15640);
        int* gt = (int*)(smem + 17204);
        int* offsG = (int*)(smem + 18768);
        unsigned int* stage = (unsigned int*)(smem + 20336); // 32 KB
        const int lane = t & 63, wid = t >> 6;
        const int tile = (int)blockIdx.x - K1_TILES;
        const long e0 = (long)tile * PT_TILE;
        const int cnt = (int)min((long)PT_TILE, (long)E_EDGES - e0);
        for (int i = t; i < NB; i += 256) {
            hist[0][i] = 0; hist[1][i] = 0; hist[2][i] = 0; hist[3][i] = 0;
            gt[i] = ghist[i];
        }
        __syncthreads();
        unsigned int v[PT_TILE / 256];
#pragma unroll
        for (int k = 0; k < PT_TILE / 256; ++k) {
            int i = t + k * 256;
            if (i < cnt) {
                int d = dst[e0 + i];
                v[k] = ((unsigned int)d << 16) | (unsigned int)src[e0 + i];
                atomicAdd(&hist[wid][d >> 7], 1);
            } else v[k] = 0xFFFFFFFFu;
        }
        __syncthreads();
        for (int i = t; i < NB; i += 256) {
            int h0 = hist[0][i], h1 = hist[1][i], h2 = hist[2][i], h3 = hist[3][i];
            hist[0][i] = 0; hist[1][i] = h0; hist[2][i] = h0 + h1; hist[3][i] = h0 + h1 + h2;
            tot[i] = h0 + h1 + h2 + h3;
        }
        __syncthreads();
        if (wid == 0) {
            int run = 0;
            for (int c = 0; c < (NB + 63) / 64; ++c) {
                int i = c * 64 + lane;
                int vv = (i < NB) ? tot[i] : 0;
                int incl = vv;
#pragma unroll
                for (int off = 1; off < 64; off <<= 1) {
                    int o = __shfl_up(incl, off, 64);
                    if (lane >= off) incl += o;
                }
                if (i < NB) offs[i] = run + incl - vv;
                run += __shfl(incl, 63, 64);
            }
        } else if (wid == 1) {
            int run = 0;
            for (int c = 0; c < (NB + 63) / 64; ++c) {
                int i = c * 64 + lane;
                int vv = (i < NB) ? gt[i] : 0;
                int incl = vv;
#pragma unroll
                for (int off = 1; off < 64; off <<= 1) {
                    int o = __shfl_up(incl, off, 64);
                    if (lane >= off) incl += o;
                }
                if (i < NB) offsG[i] = run + incl - vv;
                run += __shfl(incl, 63, 64);
            }
        }
        __syncthreads();
        for (int i = t; i < NB; i += 256) {
            int tt2 = tot[i];
            base_s[i] = offsG[i] + (tt2 ? atomicAdd(&cursor0[i], tt2) : 0);
            int ob = offs[i];
            lcur[0][i] = ob + hist[0][i];
            lcur[1][i] = ob + hist[1][i];
            lcur[2][i] = ob + hist[2][i];
            lcur[3][i] = ob + hist[3][i];
        }
        __syncthreads();
#pragma unroll
        for (int k = 0; k < PT_TILE / 256; ++k) {
            if (v[k] != 0xFFFFFFFFu) {
                int bb = v[k] >> 23;
                int pos = atomicAdd(&lcur[wid][bb], 1);
                stage[pos] = v[k];
            }
        }
        __syncthreads();
        for (int i = t; i < cnt; i += 256) {
            unsigned int p = stage[i];
            int bb = p >> 23;
            part[base_s[bb] + (i - offs[bb])] = p & 0x7FFFFFu;  // (dst&127)<<16 | src
        }
    }
}

// FB (R10 body, reverted): fine fill; s0 via in-block ghist reduce; two-pass part
// read (18 KB LDS -> high occupancy; R11's 52 KB LDS stash regressed).
__global__ void __launch_bounds__(256) fb_fill(const unsigned int* __restrict__ part,
                                               const int* __restrict__ ghist,
                                               int* __restrict__ rowstart,
                                               ushort_t* __restrict__ csr_src) {
    const int b = blockIdx.x, t = threadIdx.x, lane = t & 63, wid = t >> 6;
    __shared__ int degl[4][128], totl[128], offl[128], curl[4][128];
    __shared__ int red[4], s0s[2];
    __shared__ ushort_t lsrc[FB_CAP];  // 16 KB
    {
        int partial = 0;
        for (int i = t; i < b; i += 256) partial += ghist[i];
#pragma unroll
        for (int off = 32; off; off >>= 1) partial += __shfl_xor(partial, off);
        if (lane == 0) red[wid] = partial;
        if (t < 128) { degl[0][t] = 0; degl[1][t] = 0; degl[2][t] = 0; degl[3][t] = 0; }
        __syncthreads();
        if (t == 0) {
            int s0 = red[0] + red[1] + red[2] + red[3];
            s0s[0] = s0;
            s0s[1] = s0 + ghist[b];
        }
        __syncthreads();
    }
    const int s0 = s0s[0], s1 = s0s[1];
    const int cnt = s1 - s0;
    for (int i = t; i < cnt; i += 256) {
        unsigned int p = part[s0 + i];
        atomicAdd(&degl[wid][p >> 16], 1);
    }
    __syncthreads();
    if (t < 128) {
        int d0 = degl[0][t], d1 = degl[1][t], d2 = degl[2][t], d3 = degl[3][t];
        degl[0][t] = 0; degl[1][t] = d0; degl[2][t] = d0 + d1; degl[3][t] = d0 + d1 + d2;
        totl[t] = d0 + d1 + d2 + d3;
    }
    __syncthreads();
    if (wid == 0) {
        int run = 0;
        for (int c = 0; c < 2; ++c) {
            int i = c * 64 + lane;
            int vv = totl[i];
            int incl = vv;
#pragma unroll
            for (int off = 1; off < 64; off <<= 1) {
                int o = __shfl_up(incl, off, 64);
                if (lane >= off) incl += o;
            }
            offl[i] = run + incl - vv;
            run += __shfl(incl, 63, 64);
        }
    }
    __syncthreads();
    if (t < 128) {
        int ob = offl[t];
        curl[0][t] = ob + degl[0][t];
        curl[1][t] = ob + degl[1][t];
        curl[2][t] = ob + degl[2][t];
        curl[3][t] = ob + degl[3][t];
        int node = (b << 7) + t;
        if (node < N_NODES) rowstart[node] = s0 + ob;
    }
    if (b == 0 && t == 0) rowstart[N_NODES] = E_EDGES;
    __syncthreads();
    if (cnt <= FB_CAP) {
        for (int i = t; i < cnt; i += 256) {
            unsigned int p = part[s0 + i];
            int pos = atomicAdd(&curl[wid][p >> 16], 1);
            lsrc[pos] = (ushort_t)(p & 0xFFFFu);
        }
        __syncthreads();
        for (int i = t; i < cnt; i += 256) csr_src[s0 + i] = lsrc[i];
    } else {
        for (int i = t; i < cnt; i += 256) {
            unsigned int p = part[s0 + i];
            int pos = atomicAdd(&curl[wid][p >> 16], 1);
            csr_src[s0 + pos] = (ushort_t)(p & 0xFFFFu);
        }
    }
}

// K6 (R9/R10 body, proven ~46 us): per-dst softmax + aggregation, single dispatch.
__global__ void __launch_bounds__(256) k6_aggregate(
    const ushort_t* __restrict__ csr_src, const int* __restrict__ rowstart,
    const float* __restrict__ el, const float* __restrict__ er,
    const unsigned char* __restrict__ feat, const float* __restrict__ gat_bias,
    float* __restrict__ er_rd, float* __restrict__ hn) {
    __shared__ uint2 s_pk[4][64][4];  // [wave][edge][head] = {src<<7, ex bits}, 8 KB
    const int wid = threadIdx.x >> 6;
    const int lane = threadIdx.x & 63;
    const int n = blockIdx.x * 4 + wid;
    if (n >= N_NODES) return;
    const int start = rowstart[n];
    const int end = rowstart[n + 1];
    const int deg = end - start;

    const int e0 = lane >> 2;
    const int h = lane & 3;
    const float erh = er[n * 4 + h];
    float sm = 0.f;
    for (int base = 0; base < deg; base += 16) {
        const int e = base + e0;
        if (e < deg) {
            const int s = csr_src[start + e];
            const float ex = __expf(leaky(el[s * 4 + h] + erh));
            sm += ex;
            if (e < 64)
                s_pk[wid][e][h] = make_uint2((unsigned int)s << 7, __float_as_uint(ex));
        }
    }
#pragma unroll
    for (int off = 4; off <= 32; off <<= 1) sm += __shfl_xor(sm, off);
    const float rd = sm > 0.f ? 1.f / sm : 0.f;
    if (lane < 4) {
        er_rd[(size_t)n * 8 + lane] = erh;
        er_rd[(size_t)n * 8 + 4 + lane] = rd;
    }

    const int g4 = lane >> 4, gl = lane & 15;
    const int h2 = gl >> 2;
    const float rdh = __shfl(rd, h2);
    vfloat2 acc0 = {0.f, 0.f}, acc1 = {0.f, 0.f}, acc2 = {0.f, 0.f}, acc3 = {0.f, 0.f};

    if (deg <= 64) {
        const uint2* pk = &s_pk[wid][0][h2];
        const unsigned char* fg = feat + (gl << 3);
        int idx = g4;
        for (; idx + 4 < deg; idx += 8) {
            const uint2 pA = pk[idx * 4];
            const uint2 pB = pk[(idx + 4) * 4];
            const uint2 wA = *(const uint2*)(fg + pA.x);
            const uint2 wB = *(const uint2*)(fg + pB.x);
            const float exA = __uint_as_float(pA.y);
            const float exB = __uint_as_float(pB.y);
            const vfloat2 eA = {exA, exA}, eB = {exB, exB};
            acc0 += eA * __builtin_amdgcn_cvt_pk_f32_fp8(wA.x, false);
            acc1 += eA * __builtin_amdgcn_cvt_pk_f32_fp8(wA.x, true);
            acc2 += eA * __builtin_amdgcn_cvt_pk_f32_fp8(wA.y, false);
            acc3 += eA * __builtin_amdgcn_cvt_pk_f32_fp8(wA.y, true);
            acc0 += eB * __builtin_amdgcn_cvt_pk_f32_fp8(wB.x, false);
            acc1 += eB * __builtin_amdgcn_cvt_pk_f32_fp8(wB.x, true);
            acc2 += eB * __builtin_amdgcn_cvt_pk_f32_fp8(wB.y, false);
            acc3 += eB * __builtin_amdgcn_cvt_pk_f32_fp8(wB.y, true);
        }
        if (idx < deg) {
            const uint2 p = pk[idx * 4];
            const uint2 w = *(const uint2*)(fg + p.x);
            const float ex = __uint_as_float(p.y);
            const vfloat2 ev = {ex, ex};
            acc0 += ev * __builtin_amdgcn_cvt_pk_f32_fp8(w.x, false);
            acc1 += ev * __builtin_amdgcn_cvt_pk_f32_fp8(w.x, true);
            acc2 += ev * __builtin_amdgcn_cvt_pk_f32_fp8(w.y, false);
            acc3 += ev * __builtin_amdgcn_cvt_pk_f32_fp8(w.y, true);
        }
    } else {
        const float erh2 = __shfl(erh, h2);
        const unsigned char* fg = feat + (gl << 3);
        for (int e = start + g4; e < end; e += 4) {
            const unsigned int s = csr_src[e];
            const float ex = __expf(leaky(el[s * 4 + h2] + erh2));
            const vfloat2 ev = {ex, ex};
            const uint2 w = *(const uint2*)(fg + ((size_t)s << 7));
            acc0 += ev * __builtin_amdgcn_cvt_pk_f32_fp8(w.x, false);
            acc1 += ev * __builtin_amdgcn_cvt_pk_f32_fp8(w.x, true);
            acc2 += ev * __builtin_amdgcn_cvt_pk_f32_fp8(w.y, false);
            acc3 += ev * __builtin_amdgcn_cvt_pk_f32_fp8(w.y, true);
        }
    }
    {
        const vfloat2 rv = {rdh, rdh};
        acc0 *= rv; acc1 *= rv; acc2 *= rv; acc3 *= rv;
    }
#pragma unroll
    for (int off = 16; off <= 32; off <<= 1) {
        acc0.x += __shfl_xor(acc0.x, off);
        acc0.y += __shfl_xor(acc0.y, off);
        acc1.x += __shfl_xor(acc1.x, off);
        acc1.y += __shfl_xor(acc1.y, off);
        acc2.x += __shfl_xor(acc2.x, off);
        acc2.y += __shfl_xor(acc2.y, off);
        acc3.x += __shfl_xor(acc3.x, off);
        acc3.y += __shfl_xor(acc3.y, off);
    }
    if (lane < 16) {
        const float4 b0 = ((const float4*)gat_bias)[gl * 2];
        const float4 b1 = ((const float4*)gat_bias)[gl * 2 + 1];
        float4* hp = (float4*)(hn + (size_t)n * HD + gl * 8);
        hp[0] = make_float4(acc0.x + b0.x, acc0.y + b0.y, acc1.x + b0.z, acc1.y + b0.w);
        hp[1] = make_float4(acc2.x + b1.x, acc2.y + b1.y, acc3.x + b1.z, acc3.y + b1.w);
    }
}

// M2B: blocks [0,G_GRAPHS) = k7 pool+MLP (R9 body). Blocks [G_GRAPHS,+M2_EDGE_BLK)
// = attention in edge order, 8-DEEP strided ILP (4096 edges/block): R11 measured
// the edge sweep latency-bound (VALU 6%, 1.45 TB/s) -> double outstanding gathers
// per lane (24 in flight; ~96 VGPR of buffers, headroom before the 128 cliff).
__global__ void __launch_bounds__(512) m2b_mlp_attn(
    const int* __restrict__ src, const int* __restrict__ dst,
    const float* __restrict__ el, const float* __restrict__ er_rd,
    const float* __restrict__ hn, const int* __restrict__ graph_ids,
    const float* __restrict__ W1, const float* __restrict__ b1,
    const float* __restrict__ W2, const float* __restrict__ b2,
    const float* __restrict__ W3, const float* __restrict__ b3,
    float* __restrict__ a_out, float* __restrict__ out) {
    const int t = threadIdx.x;
    if (blockIdx.x < G_GRAPHS) {
        const int g = (int)blockIdx.x;
        const int tt = t & 127, part = t >> 7;
        __shared__ int bounds[2];
        __shared__ double pool[4][128];
        __shared__ double x[128], y[128];
        if (t < 2) {
            const int target = g + t;
            int lo = 0, hi = N_NODES;
            while (lo < hi) {
                int mid = (lo + hi) >> 1;
                if (graph_ids[mid] < target) lo = mid + 1; else hi = mid;
            }
            bounds[t] = lo;
        }
        __syncthreads();
        const int lo = bounds[0], hi = bounds[1];
        double s = 0.0;
        for (int n = lo + part; n < hi; n += 4) s += (double)hn[(size_t)n * HD + tt];
        pool[part][tt] = s;
        __syncthreads();
        if (t < 128) {
            const double cnt = (double)(hi - lo);
            const double sum = pool[0][t] + pool[1][t] + pool[2][t] + pool[3][t];
            const double v = sum / fmax(cnt, 1.0);
            x[t] = v > 0.0 ? v : expm1(v);
        }
        __syncthreads();
        if (t < 128) {
            double acc = (double)b1[t];
            for (int k = 0; k < HD; ++k) acc += x[k] * (double)W1[k * D1 + t];
            y[t] = acc > 0.0 ? acc : expm1(acc);
        }
        __syncthreads();
        if (t < D2) {
            double a2 = (double)b2[t];
            for (int k = 0; k < D1; ++k) a2 += y[k] * (double)W2[k * D2 + t];
            x[t] = a2 > 0.0 ? a2 : expm1(a2);
        }
        __syncthreads();
        if (t < D3) {
            double a3 = (double)b3[t];
            for (int k = 0; k < D2; ++k) a3 += x[k] * (double)W3[k * D3 + t];
            out[g * D3 + t] = (float)a3;
        }
    } else {
        const int eb = (int)blockIdx.x - G_GRAPHS;
        const long base = (long)eb * 4096 + t;
        if (eb < M2_FULL) {
            int sx[8], dx[8];
#pragma unroll
            for (int k = 0; k < 8; ++k) {
                const long e = base + (long)k * 512;
                sx[k] = src[e];
                dx[k] = dst[e];
            }
            float4 el4[8], er4[8], r4[8];
#pragma unroll
            for (int k = 0; k < 8; ++k) {
                el4[k] = *(const float4*)(el + sx[k] * 4);
                er4[k] = *(const float4*)(er_rd + (size_t)dx[k] * 8);
                r4[k] = *(const float4*)(er_rd + (size_t)dx[k] * 8 + 4);
            }
#pragma unroll
            for (int k = 0; k < 8; ++k) {
                vfloat4 a;
                a.x = __expf(leaky(el4[k].x + er4[k].x)) * r4[k].x;
                a.y = __expf(leaky(el4[k].y + er4[k].y)) * r4[k].y;
                a.z = __expf(leaky(el4[k].z + er4[k].z)) * r4[k].z;
                a.w = __expf(leaky(el4[k].w + er4[k].w)) * r4[k].w;
                __builtin_nontemporal_store(a, (vfloat4*)a_out + (base + (long)k * 512));
            }
        } else {
            for (int k = 0; k < 8; ++k) {
                const long e = base + (long)k * 512;
                if (e < E_EDGES) {
                    const int s = src[e], d = dst[e];
                    const float4 el4 = *(const float4*)(el + s * 4);
                    const float4 er4 = *(const float4*)(er_rd + (size_t)d * 8);
                    const float4 r4 = *(const float4*)(er_rd + (size_t)d * 8 + 4);
                    vfloat4 a;
                    a.x = __expf(leaky(el4.x + er4.x)) * r4.x;
                    a.y = __expf(leaky(el4.y + er4.y)) * r4.y;
                    a.z = __expf(leaky(el4.z + er4.z)) * r4.z;
                    a.w = __expf(leaky(el4.w + er4.w)) * r4.w;
                    __builtin_nontemporal_store(a, (vfloat4*)a_out + e);
                }
            }
        }
    }
}

extern "C" void kernel_launch(void* const* d_in, const int* in_sizes, int n_in,
                              void* d_out, int out_size, void* d_ws, size_t ws_size,
                              hipStream_t stream) {
    const float* feature = (const float*)d_in[0];
    const int* src = (const int*)d_in[1];
    const int* dst = (const int*)d_in[2];
    const int* graph_ids = (const int*)d_in[3];
    const float* W0 = (const float*)d_in[4];
    const float* b0 = (const float*)d_in[5];
    const float* Wfc = (const float*)d_in[6];
    const float* attn_l = (const float*)d_in[7];
    const float* attn_r = (const float*)d_in[8];
    const float* gat_bias = (const float*)d_in[9];
    const float* W1 = (const float*)d_in[10];
    const float* b1 = (const float*)d_in[11];
    const float* W2 = (const float*)d_in[12];
    const float* b2 = (const float*)d_in[13];
    const float* W3 = (const float*)d_in[14];
    const float* b3 = (const float*)d_in[15];

    char* ws = (char*)d_ws;
    size_t off = 0;
    auto carve = [&](size_t bytes) -> void* {
        void* p = ws + off;
        off += (bytes + 255) & ~(size_t)255;
        return p;
    };
    int* ghist = (int*)carve((size_t)NB * 4);
    int* cursor0 = (int*)carve((size_t)NB * 4);
    const size_t zero_span = off;                       // ghist + cursor0
    float* Wc = (float*)carve((size_t)IN_DIM * HD * 4);
    float* bc = (float*)carve((size_t)HD * 4);
    unsigned char* feat = (unsigned char*)carve((size_t)N_NODES * HD);
    float* el = (float*)carve((size_t)N_NODES * 4 * 4);
    float* er = (float*)carve((size_t)N_NODES * 4 * 4);
    float* er_rd = (float*)carve((size_t)N_NODES * 8 * 4);
    int* rowstart = (int*)carve((size_t)(N_NODES + 1) * 4);
    unsigned int* part = (unsigned int*)carve((size_t)E_EDGES * 4);
    ushort_t* csr_src = (ushort_t*)carve((size_t)E_EDGES * 2);
    float* hn = (float*)carve((size_t)N_NODES * HD * 4);

    float* out = (float*)d_out;
    float* a_out = out + G_GRAPHS * D3;

    (void)hipMemsetAsync(d_ws, 0, zero_span, stream);
    k0hg<<<HT_BLOCKS + 33, 256, 0, stream>>>(dst, ghist, W0, b0, Wfc, Wc, bc);
    k1pt<<<K1_TILES + PT_BLOCKS, 256, 0, stream>>>(feature, Wc, bc, attn_l, attn_r,
                                                   src, dst, ghist, cursor0,
                                                   feat, el, er, part);
    fb_fill<<<NB, 256, 0, stream>>>(part, ghist, rowstart, csr_src);
    k6_aggregate<<<(N_NODES + 3) / 4, 256, 0, stream>>>(csr_src, rowstart, el, er, feat,
                                                        gat_bias, er_rd, hn);
    m2b_mlp_attn<<<G_GRAPHS + M2_EDGE_BLK, 512, 0, stream>>>(src, dst, el, er_rd, hn,
                                                             graph_ids, W1, b1, W2, b2,
                                                             W3, b3, a_out, out);
}

// Round 14
// 214.513 us; speedup vs baseline: 1.1396x; 1.0877x over previous
//
#include <hip/hip_runtime.h>
#include <hip/hip_fp16.h>
#include <math.h>

#define N_NODES 50000
#define E_EDGES 1600000
#define G_GRAPHS 512
#define IN_DIM 64
#define EMBED 128
#define HD 128
#define NHEAD 4
#define D1 128
#define D2 64
#define D3 16
#define NEG_SLOPE 0.2f
#define NB ((N_NODES + 127) >> 7)                       // 391 coarse buckets (128 nodes)
#define HT_TILE 4096
#define HT_BLOCKS ((E_EDGES + HT_TILE - 1) / HT_TILE)   // 391 (k0hg hist tiles)
#define PT_TILE 8192
#define PT_BLOCKS ((E_EDGES + PT_TILE - 1) / PT_TILE)   // 196 (partition tiles)
#define K1_TILES ((N_NODES + 63) / 64)                  // 782 (GEMM tiles)
#define FB_CAP 8192
#define M2_EDGE_BLK ((E_EDGES + 2047) / 2048)           // 782 edge blocks @512thr x4

typedef float vfloat4 __attribute__((ext_vector_type(4)));
typedef float vfloat2 __attribute__((ext_vector_type(2)));
typedef unsigned short ushort_t;

static __device__ __forceinline__ float leaky(float x) { return x > 0.f ? x : NEG_SLOPE * x; }

// K0+HG (R10 body): blocks [0,HT_BLOCKS) coarse dst-histogram; rest Wc/bc.
__global__ void __launch_bounds__(256) k0hg(const int* __restrict__ dst, int* __restrict__ ghist,
                                            const float* __restrict__ W0, const float* __restrict__ b0,
                                            const float* __restrict__ Wfc, float* __restrict__ Wc,
                                            float* __restrict__ bc) {
    __shared__ int lh[NB];
    const int t = threadIdx.x;
    if (blockIdx.x < HT_BLOCKS) {
        for (int i = t; i < NB; i += 256) lh[i] = 0;
        __syncthreads();
        const long e0 = (long)blockIdx.x * HT_TILE;
#pragma unroll
        for (int k = 0; k < HT_TILE / 256; ++k) {
            long e = e0 + t + k * 256;
            if (e < E_EDGES) atomicAdd(&lh[dst[e] >> 7], 1);
        }
        __syncthreads();
        for (int i = t; i < NB; i += 256) {
            int v = lh[i];
            if (v) atomicAdd(&ghist[i], v);
        }
    } else {
        int tid = (int)(blockIdx.x - HT_BLOCKS) * 256 + t;
        if (tid < IN_DIM * HD) {
            int i = tid >> 7, j = tid & 127;
            float acc = 0.f;
            for (int k = 0; k < EMBED; ++k) acc += W0[i * EMBED + k] * Wfc[k * HD + j];
            Wc[tid] = acc;
        } else if (tid < IN_DIM * HD + HD) {
            int j = tid - IN_DIM * HD;
            float acc = 0.f;
            for (int k = 0; k < EMBED; ++k) acc += b0[k] * Wfc[k * HD + j];
            bc[j] = acc;
        }
    }
}

// K1PT: one dispatch, two INDEPENDENT proven bodies. HEAVY pt blocks FIRST
// ([0,PT_BLOCKS)) so they overlap the k1 stream instead of forming a serial tail
// (R12 lesson: long blocks at the grid end start after the short ones drain).
#define SMEM_BYTES 53248
__global__ void __launch_bounds__(256) k1pt(
    const float* __restrict__ A, const float* __restrict__ W,
    const float* __restrict__ b, const float* __restrict__ attn_l,
    const float* __restrict__ attn_r,
    const int* __restrict__ src, const int* __restrict__ dst,
    const int* __restrict__ ghist, int* __restrict__ cursor0,
    unsigned char* __restrict__ feat, float* __restrict__ el,
    float* __restrict__ er, unsigned int* __restrict__ part) {
    __shared__ __align__(16) char smem[SMEM_BYTES];
    const int t = threadIdx.x;
    if (blockIdx.x >= PT_BLOCKS) {
        // ---------------- k1 GEMM body (R10, byte-identical logic) ----------------
        float* Ws = (float*)smem;                         // 32 KB [k][c]
        float(*As)[68] = (float(*)[68])(smem + 32768);    // 17 KB [row][k]
        const int cc = t & 31, rt = t >> 5;
        const int c0 = cc * 4, r0 = rt * 8;
        const int row0 = ((int)blockIdx.x - PT_BLOCKS) * 64;
        {
            const float4* Wg = (const float4*)W;
            float4* Wl = (float4*)smem;
#pragma unroll
            for (int j = 0; j < (IN_DIM * HD / 4) / 256; ++j) Wl[t + j * 256] = Wg[t + j * 256];
        }
#pragma unroll
        for (int j = 0; j < 4; ++j) {
            int i2 = t + j * 256;
            int row = i2 >> 4, kq = i2 & 15;
            int gr = row0 + row;
            float4 v = (gr < N_NODES) ? *(const float4*)(A + (size_t)gr * IN_DIM + kq * 4)
                                      : make_float4(0.f, 0.f, 0.f, 0.f);
            *(float4*)&As[row][kq * 4] = v;
        }
        __syncthreads();
        float acc[8][4];
#pragma unroll
        for (int i = 0; i < 8; ++i)
#pragma unroll
            for (int j = 0; j < 4; ++j) acc[i][j] = 0.f;
        for (int k4 = 0; k4 < IN_DIM / 4; ++k4) {
            vfloat4 w0 = *(const vfloat4*)&Ws[(k4 * 4 + 0) * HD + c0];
            vfloat4 w1 = *(const vfloat4*)&Ws[(k4 * 4 + 1) * HD + c0];
            vfloat4 w2 = *(const vfloat4*)&Ws[(k4 * 4 + 2) * HD + c0];
            vfloat4 w3 = *(const vfloat4*)&Ws[(k4 * 4 + 3) * HD + c0];
#pragma unroll
            for (int i = 0; i < 8; ++i) {
                vfloat4 a = *(const vfloat4*)&As[r0 + i][k4 * 4];
#pragma unroll
                for (int j = 0; j < 4; ++j)
                    acc[i][j] += a.x * w0[j] + a.y * w1[j] + a.z * w2[j] + a.w * w3[j];
            }
        }
        {
            vfloat4 bcv = *(const vfloat4*)(b + c0);
#pragma unroll
            for (int i = 0; i < 8; ++i)
#pragma unroll
                for (int j = 0; j < 4; ++j) acc[i][j] += bcv[j];
        }
#pragma unroll
        for (int i = 0; i < 8; ++i) {
            int gr = row0 + r0 + i;
            if (gr < N_NODES) {
                unsigned int ww = __builtin_amdgcn_cvt_pk_fp8_f32(acc[i][0], acc[i][1], 0, false);
                ww = __builtin_amdgcn_cvt_pk_fp8_f32(acc[i][2], acc[i][3], ww, true);
                *(unsigned int*)(feat + (size_t)gr * HD + c0) = ww;
            }
        }
        {
            vfloat4 al = *(const vfloat4*)(attn_l + c0);
            vfloat4 ar = *(const vfloat4*)(attn_r + c0);
            float pl[8], pr[8];
#pragma unroll
            for (int i = 0; i < 8; ++i) {
                pl[i] = acc[i][0] * al[0] + acc[i][1] * al[1] + acc[i][2] * al[2] + acc[i][3] * al[3];
                pr[i] = acc[i][0] * ar[0] + acc[i][1] * ar[1] + acc[i][2] * ar[2] + acc[i][3] * ar[3];
            }
#pragma unroll
            for (int off = 1; off <= 4; off <<= 1) {
#pragma unroll
                for (int i = 0; i < 8; ++i) {
                    pl[i] += __shfl_xor(pl[i], off);
                    pr[i] += __shfl_xor(pr[i], off);
                }
            }
            if ((cc & 7) == 0) {
                const int h = cc >> 3;
#pragma unroll
                for (int i = 0; i < 8; ++i) {
                    int gr = row0 + r0 + i;
                    if (gr < N_NODES) {
                        el[gr * 4 + h] = pl[i];
                        er[gr * 4 + h] = pr[i];
                    }
                }
            }
        }
    } else {
        // ---------------- pt partition body (R10 logic, TILE=8192) ----------------
        int(*hist)[NB] = (int(*)[NB])smem;                   // 6256 B
        int(*lcur)[NB] = (int(*)[NB])(smem + 6256);          // 6256 B
        int* tot = (int*)(smem + 12512);
        int* offs = (int*)(smem + 14076);
        int* base_s = (int*)(smem + 15640);
        int* gt = (int*)(smem + 17204);
        int* offsG = (int*)(smem + 18768);
        unsigned int* stage = (unsigned int*)(smem + 20336); // 32 KB
        const int lane = t & 63, wid = t >> 6;
        const int tile = (int)blockIdx.x;
        const long e0 = (long)tile * PT_TILE;
        const int cnt = (int)min((long)PT_TILE, (long)E_EDGES - e0);
        for (int i = t; i < NB; i += 256) {
            hist[0][i] = 0; hist[1][i] = 0; hist[2][i] = 0; hist[3][i] = 0;
            gt[i] = ghist[i];
        }
        __syncthreads();
        unsigned int v[PT_TILE / 256];
#pragma unroll
        for (int k = 0; k < PT_TILE / 256; ++k) {
            int i = t + k * 256;
            if (i < cnt) {
                int d = dst[e0 + i];
                v[k] = ((unsigned int)d << 16) | (unsigned int)src[e0 + i];
                atomicAdd(&hist[wid][d >> 7], 1);
            } else v[k] = 0xFFFFFFFFu;
        }
        __syncthreads();
        for (int i = t; i < NB; i += 256) {
            int h0 = hist[0][i], h1 = hist[1][i], h2 = hist[2][i], h3 = hist[3][i];
            hist[0][i] = 0; hist[1][i] = h0; hist[2][i] = h0 + h1; hist[3][i] = h0 + h1 + h2;
            tot[i] = h0 + h1 + h2 + h3;
        }
        __syncthreads();
        if (wid == 0) {
            int run = 0;
            for (int c = 0; c < (NB + 63) / 64; ++c) {
                int i = c * 64 + lane;
                int vv = (i < NB) ? tot[i] : 0;
                int incl = vv;
#pragma unroll
                for (int off = 1; off < 64; off <<= 1) {
                    int o = __shfl_up(incl, off, 64);
                    if (lane >= off) incl += o;
                }
                if (i < NB) offs[i] = run + incl - vv;
                run += __shfl(incl, 63, 64);
            }
        } else if (wid == 1) {
            int run = 0;
            for (int c = 0; c < (NB + 63) / 64; ++c) {
                int i = c * 64 + lane;
                int vv = (i < NB) ? gt[i] : 0;
                int incl = vv;
#pragma unroll
                for (int off = 1; off < 64; off <<= 1) {
                    int o = __shfl_up(incl, off, 64);
                    if (lane >= off) incl += o;
                }
                if (i < NB) offsG[i] = run + incl - vv;
                run += __shfl(incl, 63, 64);
            }
        }
        __syncthreads();
        for (int i = t; i < NB; i += 256) {
            int tt2 = tot[i];
            base_s[i] = offsG[i] + (tt2 ? atomicAdd(&cursor0[i], tt2) : 0);
            int ob = offs[i];
            lcur[0][i] = ob + hist[0][i];
            lcur[1][i] = ob + hist[1][i];
            lcur[2][i] = ob + hist[2][i];
            lcur[3][i] = ob + hist[3][i];
        }
        __syncthreads();
#pragma unroll
        for (int k = 0; k < PT_TILE / 256; ++k) {
            if (v[k] != 0xFFFFFFFFu) {
                int bb = v[k] >> 23;
                int pos = atomicAdd(&lcur[wid][bb], 1);
                stage[pos] = v[k];
            }
        }
        __syncthreads();
        for (int i = t; i < cnt; i += 256) {
            unsigned int p = stage[i];
            int bb = p >> 23;
            part[base_s[bb] + (i - offs[bb])] = p & 0x7FFFFFu;  // (dst&127)<<16 | src
        }
    }
}

// FB (R10 body): fine fill; s0 via in-block ghist reduce; two-pass part read.
__global__ void __launch_bounds__(256) fb_fill(const unsigned int* __restrict__ part,
                                               const int* __restrict__ ghist,
                                               int* __restrict__ rowstart,
                                               ushort_t* __restrict__ csr_src) {
    const int b = blockIdx.x, t = threadIdx.x, lane = t & 63, wid = t >> 6;
    __shared__ int degl[4][128], totl[128], offl[128], curl[4][128];
    __shared__ int red[4], s0s[2];
    __shared__ ushort_t lsrc[FB_CAP];  // 16 KB
    {
        int partial = 0;
        for (int i = t; i < b; i += 256) partial += ghist[i];
#pragma unroll
        for (int off = 32; off; off >>= 1) partial += __shfl_xor(partial, off);
        if (lane == 0) red[wid] = partial;
        if (t < 128) { degl[0][t] = 0; degl[1][t] = 0; degl[2][t] = 0; degl[3][t] = 0; }
        __syncthreads();
        if (t == 0) {
            int s0 = red[0] + red[1] + red[2] + red[3];
            s0s[0] = s0;
            s0s[1] = s0 + ghist[b];
        }
        __syncthreads();
    }
    const int s0 = s0s[0], s1 = s0s[1];
    const int cnt = s1 - s0;
    for (int i = t; i < cnt; i += 256) {
        unsigned int p = part[s0 + i];
        atomicAdd(&degl[wid][p >> 16], 1);
    }
    __syncthreads();
    if (t < 128) {
        int d0 = degl[0][t], d1 = degl[1][t], d2 = degl[2][t], d3 = degl[3][t];
        degl[0][t] = 0; degl[1][t] = d0; degl[2][t] = d0 + d1; degl[3][t] = d0 + d1 + d2;
        totl[t] = d0 + d1 + d2 + d3;
    }
    __syncthreads();
    if (wid == 0) {
        int run = 0;
        for (int c = 0; c < 2; ++c) {
            int i = c * 64 + lane;
            int vv = totl[i];
            int incl = vv;
#pragma unroll
            for (int off = 1; off < 64; off <<= 1) {
                int o = __shfl_up(incl, off, 64);
                if (lane >= off) incl += o;
            }
            offl[i] = run + incl - vv;
            run += __shfl(incl, 63, 64);
        }
    }
    __syncthreads();
    if (t < 128) {
        int ob = offl[t];
        curl[0][t] = ob + degl[0][t];
        curl[1][t] = ob + degl[1][t];
        curl[2][t] = ob + degl[2][t];
        curl[3][t] = ob + degl[3][t];
        int node = (b << 7) + t;
        if (node < N_NODES) rowstart[node] = s0 + ob;
    }
    if (b == 0 && t == 0) rowstart[N_NODES] = E_EDGES;
    __syncthreads();
    if (cnt <= FB_CAP) {
        for (int i = t; i < cnt; i += 256) {
            unsigned int p = part[s0 + i];
            int pos = atomicAdd(&curl[wid][p >> 16], 1);
            lsrc[pos] = (ushort_t)(p & 0xFFFFu);
        }
        __syncthreads();
        for (int i = t; i < cnt; i += 256) csr_src[s0 + i] = lsrc[i];
    } else {
        for (int i = t; i < cnt; i += 256) {
            unsigned int p = part[s0 + i];
            int pos = atomicAdd(&curl[wid][p >> 16], 1);
            csr_src[s0 + pos] = (ushort_t)(p & 0xFFFFu);
        }
    }
}

// K6 (R10 body, proven ~46 us): per-dst softmax + aggregation; hn -> workspace.
__global__ void __launch_bounds__(256) k6_aggregate(
    const ushort_t* __restrict__ csr_src, const int* __restrict__ rowstart,
    const float* __restrict__ el, const float* __restrict__ er,
    const unsigned char* __restrict__ feat, const float* __restrict__ gat_bias,
    float* __restrict__ er_rd, float* __restrict__ hn) {
    __shared__ uint2 s_pk[4][64][4];  // [wave][edge][head] = {src<<7, ex bits}, 8 KB
    const int wid = threadIdx.x >> 6;
    const int lane = threadIdx.x & 63;
    const int n = blockIdx.x * 4 + wid;
    if (n >= N_NODES) return;
    const int start = rowstart[n];
    const int end = rowstart[n + 1];
    const int deg = end - start;

    const int e0 = lane >> 2;
    const int h = lane & 3;
    const float erh = er[n * 4 + h];
    float sm = 0.f;
    for (int base = 0; base < deg; base += 16) {
        const int e = base + e0;
        if (e < deg) {
            const int s = csr_src[start + e];
            const float ex = __expf(leaky(el[s * 4 + h] + erh));
            sm += ex;
            if (e < 64)
                s_pk[wid][e][h] = make_uint2((unsigned int)s << 7, __float_as_uint(ex));
        }
    }
#pragma unroll
    for (int off = 4; off <= 32; off <<= 1) sm += __shfl_xor(sm, off);
    const float rd = sm > 0.f ? 1.f / sm : 0.f;
    if (lane < 4) {
        er_rd[(size_t)n * 8 + lane] = erh;
        er_rd[(size_t)n * 8 + 4 + lane] = rd;
    }

    const int g4 = lane >> 4, gl = lane & 15;
    const int h2 = gl >> 2;
    const float rdh = __shfl(rd, h2);
    vfloat2 acc0 = {0.f, 0.f}, acc1 = {0.f, 0.f}, acc2 = {0.f, 0.f}, acc3 = {0.f, 0.f};

    if (deg <= 64) {
        const uint2* pk = &s_pk[wid][0][h2];
        const unsigned char* fg = feat + (gl << 3);
        int idx = g4;
        for (; idx + 4 < deg; idx += 8) {
            const uint2 pA = pk[idx * 4];
            const uint2 pB = pk[(idx + 4) * 4];
            const uint2 wA = *(const uint2*)(fg + pA.x);
            const uint2 wB = *(const uint2*)(fg + pB.x);
            const float exA = __uint_as_float(pA.y);
            const float exB = __uint_as_float(pB.y);
            const vfloat2 eA = {exA, exA}, eB = {exB, exB};
            acc0 += eA * __builtin_amdgcn_cvt_pk_f32_fp8(wA.x, false);
            acc1 += eA * __builtin_amdgcn_cvt_pk_f32_fp8(wA.x, true);
            acc2 += eA * __builtin_amdgcn_cvt_pk_f32_fp8(wA.y, false);
            acc3 += eA * __builtin_amdgcn_cvt_pk_f32_fp8(wA.y, true);
            acc0 += eB * __builtin_amdgcn_cvt_pk_f32_fp8(wB.x, false);
            acc1 += eB * __builtin_amdgcn_cvt_pk_f32_fp8(wB.x, true);
            acc2 += eB * __builtin_amdgcn_cvt_pk_f32_fp8(wB.y, false);
            acc3 += eB * __builtin_amdgcn_cvt_pk_f32_fp8(wB.y, true);
        }
        if (idx < deg) {
            const uint2 p = pk[idx * 4];
            const uint2 w = *(const uint2*)(fg + p.x);
            const float ex = __uint_as_float(p.y);
            const vfloat2 ev = {ex, ex};
            acc0 += ev * __builtin_amdgcn_cvt_pk_f32_fp8(w.x, false);
            acc1 += ev * __builtin_amdgcn_cvt_pk_f32_fp8(w.x, true);
            acc2 += ev * __builtin_amdgcn_cvt_pk_f32_fp8(w.y, false);
            acc3 += ev * __builtin_amdgcn_cvt_pk_f32_fp8(w.y, true);
        }
    } else {
        const float erh2 = __shfl(erh, h2);
        const unsigned char* fg = feat + (gl << 3);
        for (int e = start + g4; e < end; e += 4) {
            const unsigned int s = csr_src[e];
            const float ex = __expf(leaky(el[s * 4 + h2] + erh2));
            const vfloat2 ev = {ex, ex};
            const uint2 w = *(const uint2*)(fg + ((size_t)s << 7));
            acc0 += ev * __builtin_amdgcn_cvt_pk_f32_fp8(w.x, false);
            acc1 += ev * __builtin_amdgcn_cvt_pk_f32_fp8(w.x, true);
            acc2 += ev * __builtin_amdgcn_cvt_pk_f32_fp8(w.y, false);
            acc3 += ev * __builtin_amdgcn_cvt_pk_f32_fp8(w.y, true);
        }
    }
    {
        const vfloat2 rv = {rdh, rdh};
        acc0 *= rv; acc1 *= rv; acc2 *= rv; acc3 *= rv;
    }
#pragma unroll
    for (int off = 16; off <= 32; off <<= 1) {
        acc0.x += __shfl_xor(acc0.x, off);
        acc0.y += __shfl_xor(acc0.y, off);
        acc1.x += __shfl_xor(acc1.x, off);
        acc1.y += __shfl_xor(acc1.y, off);
        acc2.x += __shfl_xor(acc2.x, off);
        acc2.y += __shfl_xor(acc2.y, off);
        acc3.x += __shfl_xor(acc3.x, off);
        acc3.y += __shfl_xor(acc3.y, off);
    }
    if (lane < 16) {
        const float4 b0 = ((const float4*)gat_bias)[gl * 2];
        const float4 b1 = ((const float4*)gat_bias)[gl * 2 + 1];
        float4* hp = (float4*)(hn + (size_t)n * HD + gl * 8);
        hp[0] = make_float4(acc0.x + b0.x, acc0.y + b0.y, acc1.x + b0.z, acc1.y + b0.w);
        hp[1] = make_float4(acc2.x + b1.x, acc2.y + b1.y, acc3.x + b1.z, acc3.y + b1.w);
    }
}

// M2B (R10 body + hn nt-load): blocks [0,G_GRAPHS) = k7 pool+MLP; blocks
// [G_GRAPHS,+M2_EDGE_BLK) = attention in edge order, 4-strided edges/thread.
// hn is a dead-end stream (read once here) -> nt-load keeps el/er_rd L2-resident
// for the concurrently-running edge blocks.
__global__ void __launch_bounds__(512) m2b_mlp_attn(
    const int* __restrict__ src, const int* __restrict__ dst,
    const float* __restrict__ el, const float* __restrict__ er_rd,
    const float* __restrict__ hn, const int* __restrict__ graph_ids,
    const float* __restrict__ W1, const float* __restrict__ b1,
    const float* __restrict__ W2, const float* __restrict__ b2,
    const float* __restrict__ W3, const float* __restrict__ b3,
    float* __restrict__ a_out, float* __restrict__ out) {
    const int t = threadIdx.x;
    if (blockIdx.x < G_GRAPHS) {
        const int g = (int)blockIdx.x;
        const int tt = t & 127, part = t >> 7;
        __shared__ int bounds[2];
        __shared__ double pool[4][128];
        __shared__ double x[128], y[128];
        if (t < 2) {
            const int target = g + t;
            int lo = 0, hi = N_NODES;
            while (lo < hi) {
                int mid = (lo + hi) >> 1;
                if (graph_ids[mid] < target) lo = mid + 1; else hi = mid;
            }
            bounds[t] = lo;
        }
        __syncthreads();
        const int lo = bounds[0], hi = bounds[1];
        double s = 0.0;
        for (int n = lo + part; n < hi; n += 4)
            s += (double)__builtin_nontemporal_load(&hn[(size_t)n * HD + tt]);
        pool[part][tt] = s;
        __syncthreads();
        if (t < 128) {
            const double cnt = (double)(hi - lo);
            const double sum = pool[0][t] + pool[1][t] + pool[2][t] + pool[3][t];
            const double v = sum / fmax(cnt, 1.0);
            x[t] = v > 0.0 ? v : expm1(v);
        }
        __syncthreads();
        if (t < 128) {
            double acc = (double)b1[t];
            for (int k = 0; k < HD; ++k) acc += x[k] * (double)W1[k * D1 + t];
            y[t] = acc > 0.0 ? acc : expm1(acc);
        }
        __syncthreads();
        if (t < D2) {
            double a2 = (double)b2[t];
            for (int k = 0; k < D1; ++k) a2 += y[k] * (double)W2[k * D2 + t];
            x[t] = a2 > 0.0 ? a2 : expm1(a2);
        }
        __syncthreads();
        if (t < D3) {
            double a3 = (double)b3[t];
            for (int k = 0; k < D2; ++k) a3 += x[k] * (double)W3[k * D3 + t];
            out[g * D3 + t] = (float)a3;
        }
    } else {
        const long base = (long)(blockIdx.x - G_GRAPHS) * 2048 + t;
        bool ok[4];
        int sx[4], dx[4];
#pragma unroll
        for (int k = 0; k < 4; ++k) {
            const long e = base + (long)k * 512;
            ok[k] = e < E_EDGES;
            const long ei = ok[k] ? e : 0;
            sx[k] = src[ei];
            dx[k] = dst[ei];
        }
        float4 el4[4], er4[4], r4[4];
#pragma unroll
        for (int k = 0; k < 4; ++k) {
            el4[k] = *(const float4*)(el + sx[k] * 4);
            er4[k] = *(const float4*)(er_rd + (size_t)dx[k] * 8);
            r4[k] = *(const float4*)(er_rd + (size_t)dx[k] * 8 + 4);
        }
#pragma unroll
        for (int k = 0; k < 4; ++k) {
            if (ok[k]) {
                vfloat4 a;
                a.x = __expf(leaky(el4[k].x + er4[k].x)) * r4[k].x;
                a.y = __expf(leaky(el4[k].y + er4[k].y)) * r4[k].y;
                a.z = __expf(leaky(el4[k].z + er4[k].z)) * r4[k].z;
                a.w = __expf(leaky(el4[k].w + er4[k].w)) * r4[k].w;
                __builtin_nontemporal_store(a, (vfloat4*)a_out + (base + (long)k * 512));
            }
        }
    }
}

extern "C" void kernel_launch(void* const* d_in, const int* in_sizes, int n_in,
                              void* d_out, int out_size, void* d_ws, size_t ws_size,
                              hipStream_t stream) {
    const float* feature = (const float*)d_in[0];
    const int* src = (const int*)d_in[1];
    const int* dst = (const int*)d_in[2];
    const int* graph_ids = (const int*)d_in[3];
    const float* W0 = (const float*)d_in[4];
    const float* b0 = (const float*)d_in[5];
    const float* Wfc = (const float*)d_in[6];
    const float* attn_l = (const float*)d_in[7];
    const float* attn_r = (const float*)d_in[8];
    const float* gat_bias = (const float*)d_in[9];
    const float* W1 = (const float*)d_in[10];
    const float* b1 = (const float*)d_in[11];
    const float* W2 = (const float*)d_in[12];
    const float* b2 = (const float*)d_in[13];
    const float* W3 = (const float*)d_in[14];
    const float* b3 = (const float*)d_in[15];

    char* ws = (char*)d_ws;
    size_t off = 0;
    auto carve = [&](size_t bytes) -> void* {
        void* p = ws + off;
        off += (bytes + 255) & ~(size_t)255;
        return p;
    };
    int* ghist = (int*)carve((size_t)NB * 4);
    int* cursor0 = (int*)carve((size_t)NB * 4);
    const size_t zero_span = off;                       // ghist + cursor0
    float* Wc = (float*)carve((size_t)IN_DIM * HD * 4);
    float* bc = (float*)carve((size_t)HD * 4);
    unsigned char* feat = (unsigned char*)carve((size_t)N_NODES * HD);
    float* el = (float*)carve((size_t)N_NODES * 4 * 4);
    float* er = (float*)carve((size_t)N_NODES * 4 * 4);
    float* er_rd = (float*)carve((size_t)N_NODES * 8 * 4);
    int* rowstart = (int*)carve((size_t)(N_NODES + 1) * 4);
    unsigned int* part = (unsigned int*)carve((size_t)E_EDGES * 4);
    ushort_t* csr_src = (ushort_t*)carve((size_t)E_EDGES * 2);
    float* hn = (float*)carve((size_t)N_NODES * HD * 4);

    float* out = (float*)d_out;
    float* a_out = out + G_GRAPHS * D3;

    (void)hipMemsetAsync(d_ws, 0, zero_span, stream);
    k0hg<<<HT_BLOCKS + 33, 256, 0, stream>>>(dst, ghist, W0, b0, Wfc, Wc, bc);
    k1pt<<<PT_BLOCKS + K1_TILES, 256, 0, stream>>>(feature, Wc, bc, attn_l, attn_r,
                                                   src, dst, ghist, cursor0,
                                                   feat, el, er, part);
    fb_fill<<<NB, 256, 0, stream>>>(part, ghist, rowstart, csr_src);
    k6_aggregate<<<(N_NODES + 3) / 4, 256, 0, stream>>>(csr_src, rowstart, el, er, feat,
                                                        gat_bias, er_rd, hn);
    m2b_mlp_attn<<<G_GRAPHS + M2_EDGE_BLK, 512, 0, stream>>>(src, dst, el, er_rd, hn,
                                                             graph_ids, W1, b1, W2, b2,
                                                             W3, b3, a_out, out);
}